// Round 12
// baseline (180.658 us; speedup 1.0000x reference)
//
#include <hip/hip_runtime.h>
#include <hip/hip_bf16.h>
#include <math.h>

#define NHEADS 8
#define HDIM   32
#define HALFD  16
#define DB     2
#define DH     512
#define DW     64
#define DC     256
#define NTOK   (DB*DW*DH)   /* 65536 tokens, t = (b*64+w)*512 + h */

typedef unsigned short u16;
typedef unsigned int   u32;
typedef short short8 __attribute__((ext_vector_type(8)));
typedef float f32x4  __attribute__((ext_vector_type(4)));

__device__ __forceinline__ float bf_lo(u32 u){ union{u32 i; float f;} c; c.i = u << 16; return c.f; }
__device__ __forceinline__ float bf_hi(u32 u){ union{u32 i; float f;} c; c.i = u & 0xffff0000u; return c.f; }
__device__ __forceinline__ float bfu(u16 u){ union{u32 i; float f;} c; c.i = ((u32)u) << 16; return c.f; }
__device__ __forceinline__ u16 f2bf(float f){
    u32 x = __float_as_uint(f);
    u32 r = (x + 0x7fffu + ((x >> 16) & 1u)) >> 16;   // RTN-even
    return (u16)r;
}
__device__ __forceinline__ u16 f2bf_fast(float f){
    return (u16)((__float_as_uint(f) + 0x8000u) >> 16);
}
// single-instruction pack: lo=bf16(a), hi=bf16(b)
__device__ __forceinline__ u32 cvtpk(float a, float b){
    u32 r; asm("v_cvt_pk_bf16_f32 %0, %1, %2" : "=v"(r) : "v"(a), "v"(b)); return r;
}
// async global->LDS DMA, 16B per lane (dest = wave-uniform base + lane*16)
__device__ __forceinline__ void gload_lds16(const u16* g, u16* l){
    __builtin_amdgcn_global_load_lds(
        (const __attribute__((address_space(1))) void*)g,
        (__attribute__((address_space(3))) void*)l, 16, 0, 0);
}

// ---------------------------------------------------------------------------
// Kernel 0: prep = rope cos/sin table (blocks 0..511) + weight convert into
// FRAG-LINEAR TILE layout (blocks 512..671):
//   Wfl : 8 tiles x 32768 u16; tile ct holds output cols [ct*128,(ct+1)*128)
//         off = ct*32768 + (ks*8 + cs*4 + nf)*512 + (g*16+lq)*8 + j
//         value = W[k=ks*32+g*8+j][n=ct*128+cs*64+nf*16+lq]
//   Wofl: 2 tiles, same formula, source Wo.
// ---------------------------------------------------------------------------
__global__ void __launch_bounds__(256) prep_kernel(
    const float* __restrict__ pos, const float* __restrict__ rope_w,
    const float* __restrict__ rope_b, float* __restrict__ cosT, float* __restrict__ sinT,
    const float* __restrict__ Wq, const float* __restrict__ Wk,
    const float* __restrict__ Wv, const float* __restrict__ Wo,
    u16* __restrict__ Wfl, u16* __restrict__ Wofl)
{
    int bid = blockIdx.x;
    if (bid < 512) {
        int id = bid * 256 + threadIdx.x;              // [0, 131072)
        int j = id & 15;
        int n = (id >> 4) & 7;
        int h = (id >> 7) & 511;
        int b = id >> 16;
        const float* pp = pos + (size_t)(b*DH + h)*4;
        float p = pp[0]*rope_w[0] + pp[1]*rope_w[1] + pp[2]*rope_w[2] + pp[3]*rope_w[3] + rope_b[0];
        int fi = n*HALFD + j;
        float freq = expf(-12.0f + (float)fi * (12.0f/127.0f));
        float ang = p * freq;                           // P_SCALE = 1
        cosT[id] = cosf(ang);
        sinT[id] = sinf(ang);
    } else {
        int eid = (bid - 512)*256 + threadIdx.x;       // [0, 40960)
        if (eid < 32768) {
            int nn = eid >> 5, k0 = (eid & 31)*8;
            const float* src; int ld, nl;
            if (nn < 512)      { src = Wq; ld = 512; nl = nn;       }
            else if (nn < 768) { src = Wk; ld = 256; nl = nn - 512; }
            else               { src = Wv; ld = 256; nl = nn - 768; }
            union { short8 s; uint4 u; } c;
            #pragma unroll
            for (int j = 0; j < 8; ++j) c.s[j] = (short)f2bf(src[(size_t)(k0+j)*ld + nl]);
            int ct = nn >> 7, r2 = nn & 127;
            int cs = r2 >> 6, nf = (r2 >> 4) & 3, lq = r2 & 15;
            int ks = k0 >> 5, g = (k0 >> 3) & 3;
            size_t off = (size_t)ct*32768 + (ks*8 + cs*4 + nf)*512 + (g*16 + lq)*8;
            *reinterpret_cast<uint4*>(Wfl + off) = c.u;
        } else {
            int e2 = eid - 32768;                      // [0, 8192)
            int nn = e2 >> 5, k0 = (e2 & 31)*8;
            union { short8 s; uint4 u; } c;
            #pragma unroll
            for (int j = 0; j < 8; ++j) c.s[j] = (short)f2bf(Wo[(size_t)(k0+j)*256 + nn]);
            int ct = nn >> 7, r2 = nn & 127;
            int cs = r2 >> 6, nf = (r2 >> 4) & 3, lq = r2 & 15;
            int ks = k0 >> 5, g = (k0 >> 3) & 3;
            size_t off = (size_t)ct*32768 + (ks*8 + cs*4 + nf)*512 + (g*16 + lq)*8;
            *reinterpret_cast<uint4*>(Wofl + off) = c.u;
        }
    }
}

// ---------------------------------------------------------------------------
// Kernel 1: MFMA projection. X(65536x256 fp32) @ W(256x1024) -> bf16 QGKV.
// X frags in 128 VGPRs; Wt tiles DMA'd via global_load_lds into a 2x64KiB
// LDS double buffer.
// ---------------------------------------------------------------------------
__global__ void __launch_bounds__(256, 1) proj_mfma_kernel(
    const float* __restrict__ x, const u16* __restrict__ Wfl, u16* __restrict__ QGKV)
{
    __shared__ u16 BUF[2][32768];   // 128 KiB
    int tid = threadIdx.x;
    int rt  = blockIdx.x;           // 512 row-tiles of 128 tokens
    int lane = tid & 63, wv = tid >> 6;
    int g = lane >> 4, lq = lane & 15;
    int rhalf = wv >> 1, cstrip = wv & 1;

    // issue Wt tile0 -> BUF[0] (async DMA, overlaps X staging)
    #pragma unroll
    for (int r = 0; r < 16; ++r)
        gload_lds16(Wfl + (r*256 + tid)*8, &BUF[0][(r*256 + tid)*8]);
    __builtin_amdgcn_sched_barrier(0);

    // stage X -> BUF[1] (fp32 -> bf16, frag-linear)
    {
        int i  = tid >> 1;        // row 0..127
        int kg = tid & 1;         // k half
        int t  = rt*128 + i;
        int bw = t >> 9, h = t & 511, b = bw >> 6, w = bw & 63;
        const float* xr = x + ((size_t)((b*DH + h)*DW + w))*DC;
        int rb = i >> 4, r = i & 15;
        #pragma unroll
        for (int kk = 0; kk < 16; ++kk) {
            int k0 = kg*128 + kk*8;
            float4 f0 = *reinterpret_cast<const float4*>(xr + k0);
            float4 f1 = *reinterpret_cast<const float4*>(xr + k0 + 4);
            uint4 c;
            c.x = cvtpk(f0.x, f0.y); c.y = cvtpk(f0.z, f0.w);
            c.z = cvtpk(f1.x, f1.y); c.w = cvtpk(f1.z, f1.w);
            int ks = k0 >> 5, gg = (k0 >> 3) & 3;
            *reinterpret_cast<uint4*>(&BUF[1][(ks*8+rb)*512 + (gg*16+r)*8]) = c;
        }
    }
    __syncthreads();

    // hoist this wave's X frags (64 tokens x K=256) into registers
    short8 xf[4][8];
    #pragma unroll
    for (int tf = 0; tf < 4; ++tf)
        #pragma unroll
        for (int ks = 0; ks < 8; ++ks) {
            union { uint4 u; short8 s; } c;
            c.u = *reinterpret_cast<const uint4*>(&BUF[1][(ks*8 + rhalf*4 + tf)*512 + lane*8]);
            xf[tf][ks] = c.s;
        }
    // xf reads must land before BUF[1] is DMA-overwritten; tile0 must land too
    asm volatile("s_waitcnt lgkmcnt(0)" ::: "memory");
    __builtin_amdgcn_sched_barrier(0);
    asm volatile("s_waitcnt vmcnt(0)" ::: "memory");
    __syncthreads();

    for (int ct = 0; ct < 8; ++ct) {
        u16* cur = BUF[ct & 1];
        u16* nxt = BUF[(ct & 1) ^ 1];
        if (ct + 1 < 8) {
            const u16* src = Wfl + (size_t)(ct + 1)*32768;
            #pragma unroll
            for (int r = 0; r < 16; ++r)
                gload_lds16(src + (r*256 + tid)*8, &nxt[(r*256 + tid)*8]);
        }
        __builtin_amdgcn_sched_barrier(0);

        int nbase = ct*128 + cstrip*64;
        f32x4 acc[4][4];          // [tf][nf]
        #pragma unroll
        for (int a = 0; a < 4; ++a)
            #pragma unroll
            for (int bb = 0; bb < 4; ++bb) acc[a][bb] = (f32x4){0.f,0.f,0.f,0.f};

        #pragma unroll
        for (int ks = 0; ks < 8; ++ks) {
            short8 wf[4];
            #pragma unroll
            for (int nf = 0; nf < 4; ++nf) {
                union { uint4 u; short8 s; } c;
                c.u = *reinterpret_cast<const uint4*>(&cur[(ks*8 + cstrip*4 + nf)*512 + lane*8]);
                wf[nf] = c.s;
            }
            #pragma unroll
            for (int tf = 0; tf < 4; ++tf)
                #pragma unroll
                for (int nf = 0; nf < 4; ++nf)
                    acc[tf][nf] = __builtin_amdgcn_mfma_f32_16x16x32_bf16(wf[nf], xf[tf][ks], acc[tf][nf], 0, 0, 0);
        }
        #pragma unroll
        for (int tf = 0; tf < 4; ++tf) {
            int trow = rt*128 + (rhalf*4 + tf)*16 + lq;
            u16* dst = QGKV + (size_t)trow*1024 + nbase;
            #pragma unroll
            for (int nf = 0; nf < 4; ++nf) {
                uint2 w2;
                w2.x = cvtpk(acc[tf][nf][0], acc[tf][nf][1]);
                w2.y = cvtpk(acc[tf][nf][2], acc[tf][nf][3]);
                *reinterpret_cast<uint2*>(dst + nf*16 + g*4) = w2;
            }
        }
        asm volatile("s_waitcnt vmcnt(0)" ::: "memory");
        __syncthreads();
    }
}

// ---------------------------------------------------------------------------
// Kernel 2: MFMA flash attention per (bw, head), fused RMSNorm+RoPE.
// 8 waves x 64 q-rows. Q normed/roped DIRECTLY INTO REGISTERS (shfl-xor
// butterfly for the row sum); K normed thread-per-row into frag-linear LDS;
// V planar LDS + ds_read_b64_tr_b16. P: per-wave 2KiB qt-parity double
// buffer, PV interleaved per qt. LDS = 32+32+16 = 80 KiB -> 2 blocks/CU.
// ---------------------------------------------------------------------------
__global__ void __launch_bounds__(512, 4) attn_kernel(
    u16* __restrict__ QGKV,
    const float* __restrict__ qnw, const float* __restrict__ knw,
    const float* __restrict__ cosT, const float* __restrict__ sinT)
{
    __shared__ u16 KL[512*32];       // K frag-linear, 32 KiB
    __shared__ u16 VL[2*8192];       // V planes: [df][key][dd], 32 KiB
    __shared__ u16 PL[8192];         // P scratch: 8 waves x (2 x 512 u16), 16 KiB

    int bid0 = blockIdx.x;           // [0,1024)
    // XCD swizzle: heads of one bw colocate on an XCD (shared QGKV lines)
    int idx  = (bid0 & 7)*128 + (bid0 >> 3);
    int bw   = idx >> 3, n = idx & 7;
    int tid  = threadIdx.x;
    int lane = tid & 63;
    int wv   = tid >> 6;
    int g    = lane >> 4;
    int lq   = lane & 15;
    int b    = bw >> 6;
    const float CSC = 0.17677669529663687f * 1.4426950408889634f;  // scale*log2e

    // ---- stage K (norm+rope, thread-per-row) and V planes ----
    {
        int i = tid;
        size_t tb = ((size_t)(bw*DH + i))*1024;
        int tbl = ((b*DH + i)*NHEADS + n)*HALFD;
        float cs[16], sn[16];
        #pragma unroll
        for (int j4 = 0; j4 < 4; ++j4) {
            float4 c4 = *reinterpret_cast<const float4*>(cosT + tbl + j4*4);
            float4 s4 = *reinterpret_cast<const float4*>(sinT + tbl + j4*4);
            cs[j4*4+0]=c4.x; cs[j4*4+1]=c4.y; cs[j4*4+2]=c4.z; cs[j4*4+3]=c4.w;
            sn[j4*4+0]=s4.x; sn[j4*4+1]=s4.y; sn[j4*4+2]=s4.z; sn[j4*4+3]=s4.w;
        }
        const u16* srcp = QGKV + tb + 512 + n*HDIM;
        uint4 rr[4];
        #pragma unroll
        for (int ii = 0; ii < 4; ++ii) rr[ii] = reinterpret_cast<const uint4*>(srcp)[ii];
        float v[32]; float ss = 0.f;
        const u32* rw = reinterpret_cast<const u32*>(rr);
        #pragma unroll
        for (int ii = 0; ii < 16; ++ii) {
            v[2*ii]   = bf_lo(rw[ii]);
            v[2*ii+1] = bf_hi(rw[ii]);
            ss += v[2*ii]*v[2*ii] + v[2*ii+1]*v[2*ii+1];
        }
        float rs = rsqrtf(ss*(1.0f/32.0f) + 1e-6f);
        #pragma unroll
        for (int d = 0; d < 32; ++d) v[d] *= rs * knw[d];
        #pragma unroll
        for (int j = 0; j < 16; ++j) {
            float e = v[2*j], o = v[2*j+1];
            v[2*j]   = e*cs[j] - o*sn[j];
            v[2*j+1] = e*sn[j] + o*cs[j];
        }
        int rb = i >> 4, r = i & 15;
        #pragma unroll
        for (int gg = 0; gg < 4; ++gg) {
            uint4 u;
            u.x = (u32)f2bf(v[8*gg+0]) | ((u32)f2bf(v[8*gg+1]) << 16);
            u.y = (u32)f2bf(v[8*gg+2]) | ((u32)f2bf(v[8*gg+3]) << 16);
            u.z = (u32)f2bf(v[8*gg+4]) | ((u32)f2bf(v[8*gg+5]) << 16);
            u.w = (u32)f2bf(v[8*gg+6]) | ((u32)f2bf(v[8*gg+7]) << 16);
            *reinterpret_cast<uint4*>(KL + rb*512 + gg*128 + r*8) = u;
        }
        // V: row-major into two 16-wide d-planes (contiguous b128 writes)
        const uint4* vsrc = reinterpret_cast<const uint4*>(QGKV + tb + 768 + n*HDIM);
        uint4 v0 = vsrc[0], v1 = vsrc[1], v2 = vsrc[2], v3 = vsrc[3];
        *reinterpret_cast<uint4*>(VL + i*16)          = v0;   // d 0..7
        *reinterpret_cast<uint4*>(VL + i*16 + 8)      = v1;   // d 8..15
        *reinterpret_cast<uint4*>(VL + 8192 + i*16)   = v2;   // d 16..23
        *reinterpret_cast<uint4*>(VL + 8192 + i*16+8) = v3;   // d 24..31
    }

    // ---- Q -> registers: lane-parallel norm (shfl butterfly) + rope ----
    short8 qf[4];
    {
        float qw[8];
        {
            float4 a = *reinterpret_cast<const float4*>(qnw + g*8);
            float4 c = *reinterpret_cast<const float4*>(qnw + g*8 + 4);
            qw[0]=a.x; qw[1]=a.y; qw[2]=a.z; qw[3]=a.w;
            qw[4]=c.x; qw[5]=c.y; qw[6]=c.z; qw[7]=c.w;
        }
        #pragma unroll
        for (int qt = 0; qt < 4; ++qt) {
            int hrow = wv*64 + qt*16 + lq;
            union { uint4 u; u32 w[4]; } qr;
            qr.u = *reinterpret_cast<const uint4*>(
                QGKV + ((size_t)(bw*DH + hrow))*1024 + n*HDIM + g*8);
            float v[8]; float ss = 0.f;
            #pragma unroll
            for (int ii = 0; ii < 4; ++ii) {
                v[2*ii]   = bf_lo(qr.w[ii]);
                v[2*ii+1] = bf_hi(qr.w[ii]);
                ss += v[2*ii]*v[2*ii] + v[2*ii+1]*v[2*ii+1];
            }
            ss += __shfl_xor(ss, 16);
            ss += __shfl_xor(ss, 32);
            float rs = rsqrtf(ss*(1.0f/32.0f) + 1e-6f) * CSC;
            int tbl = ((b*DH + hrow)*NHEADS + n)*HALFD + g*4;
            float4 c4 = *reinterpret_cast<const float4*>(cosT + tbl);
            float4 s4 = *reinterpret_cast<const float4*>(sinT + tbl);
            float cs[4] = {c4.x, c4.y, c4.z, c4.w};
            float sn[4] = {s4.x, s4.y, s4.z, s4.w};
            union { short8 s8; u32 w[4]; } o;
            #pragma unroll
            for (int p = 0; p < 4; ++p) {
                float e  = v[2*p]   * rs * qw[2*p];
                float od = v[2*p+1] * rs * qw[2*p+1];
                o.w[p] = cvtpk(e*cs[p] - od*sn[p], e*sn[p] + od*cs[p]);
            }
            qf[qt] = o.s8;
        }
    }
    __syncthreads();

    f32x4 oacc[4][2];
    float l_run[4];
    #pragma unroll
    for (int qt = 0; qt < 4; ++qt) {
        oacc[qt][0] = (f32x4){0.f,0.f,0.f,0.f};
        oacc[qt][1] = (f32x4){0.f,0.f,0.f,0.f};
        l_run[qt] = 0.f;
    }

    u16* PW = PL + wv*1024;                      // 2 x 512 u16 (qt-parity dbuf)
    const int sw = (lq ^ (lq >> 2)) & 3;
    const u32 vbase = (u32)(uintptr_t)VL + (u32)(lq*8 + g*256);

    for (int st = 0; st < 16; ++st) {
        short8 kf[2];
        #pragma unroll
        for (int kt = 0; kt < 2; ++kt) {
            union { uint4 u; short8 s; } c;
            c.u = *reinterpret_cast<const uint4*>(KL + (st*2 + kt)*512 + lane*8);
            kf[kt] = c.s;
        }
        // issue V transpose-reads early
        uint2 v00, v01, v10, v11;
        {
            u32 ta = vbase + (u32)(st*1024);
            asm volatile("ds_read_b64_tr_b16 %0, %4\n\t"
                         "ds_read_b64_tr_b16 %1, %4 offset:128\n\t"
                         "ds_read_b64_tr_b16 %2, %4 offset:16384\n\t"
                         "ds_read_b64_tr_b16 %3, %4 offset:16512"
                         : "=v"(v00), "=v"(v01), "=v"(v10), "=v"(v11)
                         : "v"(ta));
        }
        union { uint4 u; short8 s; } va0, va1;
        #pragma unroll
        for (int qt = 0; qt < 4; ++qt) {
            __builtin_amdgcn_s_setprio(1);
            f32x4 sf0 = __builtin_amdgcn_mfma_f32_16x16x32_bf16(kf[0], qf[qt], (f32x4){0.f,0.f,0.f,0.f}, 0, 0, 0);
            f32x4 sf1 = __builtin_amdgcn_mfma_f32_16x16x32_bf16(kf[1], qf[qt], (f32x4){0.f,0.f,0.f,0.f}, 0, 0, 0);
            __builtin_amdgcn_s_setprio(0);
            float p0 = __builtin_amdgcn_exp2f(sf0[0]);
            float p1 = __builtin_amdgcn_exp2f(sf0[1]);
            float p2 = __builtin_amdgcn_exp2f(sf0[2]);
            float p3 = __builtin_amdgcn_exp2f(sf0[3]);
            float p4 = __builtin_amdgcn_exp2f(sf1[0]);
            float p5 = __builtin_amdgcn_exp2f(sf1[1]);
            float p6 = __builtin_amdgcn_exp2f(sf1[2]);
            float p7 = __builtin_amdgcn_exp2f(sf1[3]);
            l_run[qt] += ((p0+p1)+(p2+p3)) + ((p4+p5)+(p6+p7));
            u16* pq = PW + (qt & 1)*512 + lq*32;
            int ch0 = ((g >> 1)    ) ^ sw;
            int ch1 = ((g >> 1) + 2) ^ sw;
            uint2 w0, w1;
            w0.x = cvtpk(p0, p1); w0.y = cvtpk(p2, p3);
            w1.x = cvtpk(p4, p5); w1.y = cvtpk(p6, p7);
            *reinterpret_cast<uint2*>(pq + ch0*8 + (g&1)*4) = w0;
            *reinterpret_cast<uint2*>(pq + ch1*8 + (g&1)*4) = w1;
            union { uint4 u; short8 s; } pb;
            pb.u = *reinterpret_cast<const uint4*>(pq + (g ^ sw)*8);
            if (qt == 0) {
                asm volatile("s_waitcnt lgkmcnt(0)" ::: "memory");
                __builtin_amdgcn_sched_barrier(0);
                va0.u = make_uint4(v00.x, v00.y, v01.x, v01.y);
                va1.u = make_uint4(v10.x, v10.y, v11.x, v11.y);
            }
            __builtin_amdgcn_s_setprio(1);
            oacc[qt][0] = __builtin_amdgcn_mfma_f32_16x16x32_bf16(va0.s, pb.s, oacc[qt][0], 0, 0, 0);
            oacc[qt][1] = __builtin_amdgcn_mfma_f32_16x16x32_bf16(va1.s, pb.s, oacc[qt][1], 0, 0, 0);
            __builtin_amdgcn_s_setprio(0);
        }
    }

    // ---- epilogue: normalize, gate, store (overwrites q columns) ----
    #pragma unroll
    for (int qt = 0; qt < 4; ++qt) {
        float lr = l_run[qt];
        lr += __shfl_xor(lr, 16);
        lr += __shfl_xor(lr, 32);
        float inv = 1.0f / lr;
        int t = bw*DH + wv*64 + qt*16 + lq;
        size_t tb = (size_t)t*1024;
        #pragma unroll
        for (int df = 0; df < 2; ++df) {
            int col = n*HDIM + 16*df + 4*g;
            ushort4 gv = *reinterpret_cast<const ushort4*>(QGKV + tb + 256 + col);
            u16 gr[4] = {gv.x, gv.y, gv.z, gv.w};
            ushort4 ov;
            u16 orr[4];
            #pragma unroll
            for (int r = 0; r < 4; ++r) {
                float o  = oacc[qt][df][r] * inv;
                float gf = bfu(gr[r]);
                float sg = 1.0f / (1.0f + __builtin_amdgcn_exp2f(-gf * 1.4426950408889634f));
                orr[r] = f2bf_fast(o * sg);
            }
            ov.x = orr[0]; ov.y = orr[1]; ov.z = orr[2]; ov.w = orr[3];
            *reinterpret_cast<ushort4*>(QGKV + tb + col) = ov;
        }
    }
}

// ---------------------------------------------------------------------------
// Kernel 3: MFMA output projection. AG(65536x256 bf16 @ QGKV ld 1024) @ Wo
// + bo -> fp32 out (scattered). Same DMA double-buffer structure, 2 tiles.
// ---------------------------------------------------------------------------
__global__ void __launch_bounds__(256, 1) outproj_mfma_kernel(
    const u16* __restrict__ QGKV, const u16* __restrict__ Wofl,
    const float* __restrict__ bo, float* __restrict__ out)
{
    __shared__ u16 BUF[2][32768];   // 128 KiB
    int tid = threadIdx.x;
    int rt  = blockIdx.x;
    int lane = tid & 63, wv = tid >> 6;
    int g = lane >> 4, lq = lane & 15;
    int rhalf = wv >> 1, cstrip = wv & 1;

    // issue Wot tile0 -> BUF[0]
    #pragma unroll
    for (int r = 0; r < 16; ++r)
        gload_lds16(Wofl + (r*256 + tid)*8, &BUF[0][(r*256 + tid)*8]);
    __builtin_amdgcn_sched_barrier(0);

    // stage A -> BUF[1] (bf16 frag-linear)
    {
        int i  = tid >> 1;
        int kg = tid & 1;
        const u16* arow = QGKV + (size_t)(rt*128 + i)*1024;
        int rb = i >> 4, r = i & 15;
        #pragma unroll
        for (int kk = 0; kk < 16; ++kk) {
            int k0 = kg*128 + kk*8;
            uint4 u = *reinterpret_cast<const uint4*>(arow + k0);
            int ks = k0 >> 5, gg = (k0 >> 3) & 3;
            *reinterpret_cast<uint4*>(&BUF[1][(ks*8+rb)*512 + (gg*16+r)*8]) = u;
        }
    }
    __syncthreads();

    short8 xf[4][8];
    #pragma unroll
    for (int tf = 0; tf < 4; ++tf)
        #pragma unroll
        for (int ks = 0; ks < 8; ++ks) {
            union { uint4 u; short8 s; } c;
            c.u = *reinterpret_cast<const uint4*>(&BUF[1][(ks*8 + rhalf*4 + tf)*512 + lane*8]);
            xf[tf][ks] = c.s;
        }
    asm volatile("s_waitcnt lgkmcnt(0)" ::: "memory");
    __builtin_amdgcn_sched_barrier(0);
    asm volatile("s_waitcnt vmcnt(0)" ::: "memory");
    __syncthreads();

    for (int ct = 0; ct < 2; ++ct) {
        u16* cur = BUF[ct & 1];
        u16* nxt = BUF[(ct & 1) ^ 1];
        if (ct + 1 < 2) {
            const u16* src = Wofl + (size_t)(ct + 1)*32768;
            #pragma unroll
            for (int r = 0; r < 16; ++r)
                gload_lds16(src + (r*256 + tid)*8, &nxt[(r*256 + tid)*8]);
        }
        __builtin_amdgcn_sched_barrier(0);

        int nbase = ct*128 + cstrip*64;
        f32x4 acc[4][4];
        #pragma unroll
        for (int a = 0; a < 4; ++a)
            #pragma unroll
            for (int bb = 0; bb < 4; ++bb) acc[a][bb] = (f32x4){0.f,0.f,0.f,0.f};

        #pragma unroll
        for (int ks = 0; ks < 8; ++ks) {
            short8 wf[4];
            #pragma unroll
            for (int nf = 0; nf < 4; ++nf) {
                union { uint4 u; short8 s; } c;
                c.u = *reinterpret_cast<const uint4*>(&cur[(ks*8 + cstrip*4 + nf)*512 + lane*8]);
                wf[nf] = c.s;
            }
            #pragma unroll
            for (int tf = 0; tf < 4; ++tf)
                #pragma unroll
                for (int nf = 0; nf < 4; ++nf)
                    acc[tf][nf] = __builtin_amdgcn_mfma_f32_16x16x32_bf16(wf[nf], xf[tf][ks], acc[tf][nf], 0, 0, 0);
        }
        #pragma unroll
        for (int tf = 0; tf < 4; ++tf) {
            int trow = rt*128 + (rhalf*4 + tf)*16 + lq;
            int bw = trow >> 9, h = trow & 511, b = bw >> 6, w = bw & 63;
            float* orow = out + ((size_t)((b*DH + h)*DW + w))*DC;
            #pragma unroll
            for (int nf = 0; nf < 4; ++nf) {
                int nn = nbase + nf*16 + g*4;
                float4 bv = *reinterpret_cast<const float4*>(bo + nn);
                float4 res;
                res.x = acc[tf][nf][0] + bv.x;
                res.y = acc[tf][nf][1] + bv.y;
                res.z = acc[tf][nf][2] + bv.z;
                res.w = acc[tf][nf][3] + bv.w;
                *reinterpret_cast<float4*>(orow + nn) = res;
            }
        }
        asm volatile("s_waitcnt vmcnt(0)" ::: "memory");
        __syncthreads();
    }
}

// ---------------------------------------------------------------------------
extern "C" void kernel_launch(void* const* d_in, const int* in_sizes, int n_in,
                              void* d_out, int out_size, void* d_ws, size_t ws_size,
                              hipStream_t stream)
{
    const float* x      = (const float*)d_in[0];
    const float* pos    = (const float*)d_in[1];
    const float* Wq     = (const float*)d_in[2];
    const float* Wk     = (const float*)d_in[3];
    const float* Wv     = (const float*)d_in[4];
    const float* Wo     = (const float*)d_in[5];
    const float* bo     = (const float*)d_in[6];
    const float* qnw    = (const float*)d_in[7];
    const float* knw    = (const float*)d_in[8];
    const float* rope_w = (const float*)d_in[9];
    const float* rope_b = (const float*)d_in[10];
    float* out = (float*)d_out;

    char* wsp = (char*)d_ws;
    u16*   QGKV = (u16*)wsp;                                  // 128 MiB
    float* cosT = (float*)(wsp + (size_t)NTOK*1024*2);        // 512 KiB
    float* sinT = cosT + DB*DH*NHEADS*HALFD;                  // 512 KiB
    u16*   Wfl  = (u16*)(sinT + DB*DH*NHEADS*HALFD);          // 512 KiB (8 tiles)
    u16*   Wofl = Wfl + 8*32768;                              // 128 KiB (2 tiles)

    prep_kernel        <<<dim3(672),  dim3(256), 0, stream>>>(pos, rope_w, rope_b, cosT, sinT,
                                                              Wq, Wk, Wv, Wo, Wfl, Wofl);
    proj_mfma_kernel   <<<dim3(512),  dim3(256), 0, stream>>>(x, Wfl, QGKV);
    attn_kernel        <<<dim3(1024), dim3(512), 0, stream>>>(QGKV, qnw, knw, cosT, sinT);
    outproj_mfma_kernel<<<dim3(512),  dim3(256), 0, stream>>>(QGKV, Wofl, bo, out);
}

// Round 15
// 180.298 us; speedup vs baseline: 1.0020x; 1.0020x over previous
//
#include <hip/hip_runtime.h>
#include <hip/hip_bf16.h>
#include <math.h>

#define NHEADS 8
#define HDIM   32
#define HALFD  16
#define DB     2
#define DH     512
#define DW     64
#define DC     256
#define NTOK   (DB*DW*DH)   /* 65536 tokens, t = (b*64+w)*512 + h */

typedef unsigned short u16;
typedef unsigned int   u32;
typedef short short8 __attribute__((ext_vector_type(8)));
typedef float f32x4  __attribute__((ext_vector_type(4)));

__device__ __forceinline__ float bf_lo(u32 u){ union{u32 i; float f;} c; c.i = u << 16; return c.f; }
__device__ __forceinline__ float bf_hi(u32 u){ union{u32 i; float f;} c; c.i = u & 0xffff0000u; return c.f; }
__device__ __forceinline__ float bfu(u16 u){ union{u32 i; float f;} c; c.i = ((u32)u) << 16; return c.f; }
__device__ __forceinline__ u16 f2bf(float f){
    u32 x = __float_as_uint(f);
    u32 r = (x + 0x7fffu + ((x >> 16) & 1u)) >> 16;   // RTN-even
    return (u16)r;
}
__device__ __forceinline__ u16 f2bf_fast(float f){
    return (u16)((__float_as_uint(f) + 0x8000u) >> 16);
}
// single-instruction pack: lo=bf16(a), hi=bf16(b)
__device__ __forceinline__ u32 cvtpk(float a, float b){
    u32 r; asm("v_cvt_pk_bf16_f32 %0, %1, %2" : "=v"(r) : "v"(a), "v"(b)); return r;
}
// async global->LDS DMA, 16B per lane (dest = wave-uniform base + lane*16)
__device__ __forceinline__ void gload_lds16(const u16* g, u16* l){
    __builtin_amdgcn_global_load_lds(
        (const __attribute__((address_space(1))) void*)g,
        (__attribute__((address_space(3))) void*)l, 16, 0, 0);
}

// ---------------------------------------------------------------------------
// Kernel 0: prep = rope cos/sin table (blocks 0..511) + weight convert into
// FRAG-LINEAR TILE layout (blocks 512..671):
//   Wfl : 8 tiles x 32768 u16; tile ct holds output cols [ct*128,(ct+1)*128)
//         off = ct*32768 + (ks*8 + cs*4 + nf)*512 + (g*16+lq)*8 + j
//         value = W[k=ks*32+g*8+j][n=ct*128+cs*64+nf*16+lq]
//   Wofl: 2 tiles, same formula, source Wo.
// ---------------------------------------------------------------------------
__global__ void __launch_bounds__(256) prep_kernel(
    const float* __restrict__ pos, const float* __restrict__ rope_w,
    const float* __restrict__ rope_b, float* __restrict__ cosT, float* __restrict__ sinT,
    const float* __restrict__ Wq, const float* __restrict__ Wk,
    const float* __restrict__ Wv, const float* __restrict__ Wo,
    u16* __restrict__ Wfl, u16* __restrict__ Wofl)
{
    int bid = blockIdx.x;
    if (bid < 512) {
        int id = bid * 256 + threadIdx.x;              // [0, 131072)
        int j = id & 15;
        int n = (id >> 4) & 7;
        int h = (id >> 7) & 511;
        int b = id >> 16;
        const float* pp = pos + (size_t)(b*DH + h)*4;
        float p = pp[0]*rope_w[0] + pp[1]*rope_w[1] + pp[2]*rope_w[2] + pp[3]*rope_w[3] + rope_b[0];
        int fi = n*HALFD + j;
        float freq = expf(-12.0f + (float)fi * (12.0f/127.0f));
        float ang = p * freq;                           // P_SCALE = 1
        cosT[id] = cosf(ang);
        sinT[id] = sinf(ang);
    } else {
        int eid = (bid - 512)*256 + threadIdx.x;       // [0, 40960)
        if (eid < 32768) {
            int nn = eid >> 5, k0 = (eid & 31)*8;
            const float* src; int ld, nl;
            if (nn < 512)      { src = Wq; ld = 512; nl = nn;       }
            else if (nn < 768) { src = Wk; ld = 256; nl = nn - 512; }
            else               { src = Wv; ld = 256; nl = nn - 768; }
            union { short8 s; uint4 u; } c;
            #pragma unroll
            for (int j = 0; j < 8; ++j) c.s[j] = (short)f2bf(src[(size_t)(k0+j)*ld + nl]);
            int ct = nn >> 7, r2 = nn & 127;
            int cs = r2 >> 6, nf = (r2 >> 4) & 3, lq = r2 & 15;
            int ks = k0 >> 5, g = (k0 >> 3) & 3;
            size_t off = (size_t)ct*32768 + (ks*8 + cs*4 + nf)*512 + (g*16 + lq)*8;
            *reinterpret_cast<uint4*>(Wfl + off) = c.u;
        } else {
            int e2 = eid - 32768;                      // [0, 8192)
            int nn = e2 >> 5, k0 = (e2 & 31)*8;
            union { short8 s; uint4 u; } c;
            #pragma unroll
            for (int j = 0; j < 8; ++j) c.s[j] = (short)f2bf(Wo[(size_t)(k0+j)*256 + nn]);
            int ct = nn >> 7, r2 = nn & 127;
            int cs = r2 >> 6, nf = (r2 >> 4) & 3, lq = r2 & 15;
            int ks = k0 >> 5, g = (k0 >> 3) & 3;
            size_t off = (size_t)ct*32768 + (ks*8 + cs*4 + nf)*512 + (g*16 + lq)*8;
            *reinterpret_cast<uint4*>(Wofl + off) = c.u;
        }
    }
}

// ---------------------------------------------------------------------------
// Kernel 1: MFMA projection. X(65536x256 fp32) @ W(256x1024) -> bf16 QGKV.
// X frags in 128 VGPRs; Wt tiles DMA'd via global_load_lds into a 2x64KiB
// LDS double buffer.
// ---------------------------------------------------------------------------
__global__ void __launch_bounds__(256, 1) proj_mfma_kernel(
    const float* __restrict__ x, const u16* __restrict__ Wfl, u16* __restrict__ QGKV)
{
    __shared__ u16 BUF[2][32768];   // 128 KiB
    int tid = threadIdx.x;
    int rt  = blockIdx.x;           // 512 row-tiles of 128 tokens
    int lane = tid & 63, wv = tid >> 6;
    int g = lane >> 4, lq = lane & 15;
    int rhalf = wv >> 1, cstrip = wv & 1;

    // issue Wt tile0 -> BUF[0] (async DMA, overlaps X staging)
    #pragma unroll
    for (int r = 0; r < 16; ++r)
        gload_lds16(Wfl + (r*256 + tid)*8, &BUF[0][(r*256 + tid)*8]);
    __builtin_amdgcn_sched_barrier(0);

    // stage X -> BUF[1] (fp32 -> bf16, frag-linear)
    {
        int i  = tid >> 1;        // row 0..127
        int kg = tid & 1;         // k half
        int t  = rt*128 + i;
        int bw = t >> 9, h = t & 511, b = bw >> 6, w = bw & 63;
        const float* xr = x + ((size_t)((b*DH + h)*DW + w))*DC;
        int rb = i >> 4, r = i & 15;
        #pragma unroll
        for (int kk = 0; kk < 16; ++kk) {
            int k0 = kg*128 + kk*8;
            float4 f0 = *reinterpret_cast<const float4*>(xr + k0);
            float4 f1 = *reinterpret_cast<const float4*>(xr + k0 + 4);
            uint4 c;
            c.x = cvtpk(f0.x, f0.y); c.y = cvtpk(f0.z, f0.w);
            c.z = cvtpk(f1.x, f1.y); c.w = cvtpk(f1.z, f1.w);
            int ks = k0 >> 5, gg = (k0 >> 3) & 3;
            *reinterpret_cast<uint4*>(&BUF[1][(ks*8+rb)*512 + (gg*16+r)*8]) = c;
        }
    }
    __syncthreads();

    // hoist this wave's X frags (64 tokens x K=256) into registers
    short8 xf[4][8];
    #pragma unroll
    for (int tf = 0; tf < 4; ++tf)
        #pragma unroll
        for (int ks = 0; ks < 8; ++ks) {
            union { uint4 u; short8 s; } c;
            c.u = *reinterpret_cast<const uint4*>(&BUF[1][(ks*8 + rhalf*4 + tf)*512 + lane*8]);
            xf[tf][ks] = c.s;
        }
    // xf reads must land before BUF[1] is DMA-overwritten; tile0 must land too
    asm volatile("s_waitcnt lgkmcnt(0)" ::: "memory");
    __builtin_amdgcn_sched_barrier(0);
    asm volatile("s_waitcnt vmcnt(0)" ::: "memory");
    __syncthreads();

    for (int ct = 0; ct < 8; ++ct) {
        u16* cur = BUF[ct & 1];
        u16* nxt = BUF[(ct & 1) ^ 1];
        if (ct + 1 < 8) {
            const u16* src = Wfl + (size_t)(ct + 1)*32768;
            #pragma unroll
            for (int r = 0; r < 16; ++r)
                gload_lds16(src + (r*256 + tid)*8, &nxt[(r*256 + tid)*8]);
        }
        __builtin_amdgcn_sched_barrier(0);

        int nbase = ct*128 + cstrip*64;
        f32x4 acc[4][4];          // [tf][nf]
        #pragma unroll
        for (int a = 0; a < 4; ++a)
            #pragma unroll
            for (int bb = 0; bb < 4; ++bb) acc[a][bb] = (f32x4){0.f,0.f,0.f,0.f};

        #pragma unroll
        for (int ks = 0; ks < 8; ++ks) {
            short8 wf[4];
            #pragma unroll
            for (int nf = 0; nf < 4; ++nf) {
                union { uint4 u; short8 s; } c;
                c.u = *reinterpret_cast<const uint4*>(&cur[(ks*8 + cstrip*4 + nf)*512 + lane*8]);
                wf[nf] = c.s;
            }
            #pragma unroll
            for (int tf = 0; tf < 4; ++tf)
                #pragma unroll
                for (int nf = 0; nf < 4; ++nf)
                    acc[tf][nf] = __builtin_amdgcn_mfma_f32_16x16x32_bf16(wf[nf], xf[tf][ks], acc[tf][nf], 0, 0, 0);
        }
        #pragma unroll
        for (int tf = 0; tf < 4; ++tf) {
            int trow = rt*128 + (rhalf*4 + tf)*16 + lq;
            u16* dst = QGKV + (size_t)trow*1024 + nbase;
            #pragma unroll
            for (int nf = 0; nf < 4; ++nf) {
                uint2 w2;
                w2.x = cvtpk(acc[tf][nf][0], acc[tf][nf][1]);
                w2.y = cvtpk(acc[tf][nf][2], acc[tf][nf][3]);
                *reinterpret_cast<uint2*>(dst + nf*16 + g*4) = w2;
            }
        }
        asm volatile("s_waitcnt vmcnt(0)" ::: "memory");
        __syncthreads();
    }
}

// ---------------------------------------------------------------------------
// Kernel 2: MFMA flash attention per (bw, head), fused RMSNorm+RoPE.
// 8 waves x 64 q-rows. Q normed/roped DIRECTLY INTO REGISTERS (shfl-xor
// butterfly for the row sum); K normed thread-per-row into frag-linear LDS;
// V planar LDS + ds_read_b64_tr_b16. P: per-wave 2KiB qt-parity double
// buffer, PV interleaved per qt. LDS = 32+32+16 = 80 KiB -> 2 blocks/CU.
// ---------------------------------------------------------------------------
__global__ void __launch_bounds__(512, 4) attn_kernel(
    u16* __restrict__ QGKV,
    const float* __restrict__ qnw, const float* __restrict__ knw,
    const float* __restrict__ cosT, const float* __restrict__ sinT)
{
    __shared__ u16 KL[512*32];       // K frag-linear, 32 KiB
    __shared__ u16 VL[2*8192];       // V planes: [df][key][dd], 32 KiB
    __shared__ u16 PL[8192];         // P scratch: 8 waves x (2 x 512 u16), 16 KiB

    int bid0 = blockIdx.x;           // [0,1024)
    // XCD swizzle: heads of one bw colocate on an XCD (shared QGKV lines)
    int idx  = (bid0 & 7)*128 + (bid0 >> 3);
    int bw   = idx >> 3, n = idx & 7;
    int tid  = threadIdx.x;
    int lane = tid & 63;
    int wv   = tid >> 6;
    int g    = lane >> 4;
    int lq   = lane & 15;
    int b    = bw >> 6;
    const float CSC = 0.17677669529663687f * 1.4426950408889634f;  // scale*log2e

    // ---- stage K (norm+rope, thread-per-row) and V planes ----
    {
        int i = tid;
        size_t tb = ((size_t)(bw*DH + i))*1024;
        int tbl = ((b*DH + i)*NHEADS + n)*HALFD;
        float cs[16], sn[16];
        #pragma unroll
        for (int j4 = 0; j4 < 4; ++j4) {
            float4 c4 = *reinterpret_cast<const float4*>(cosT + tbl + j4*4);
            float4 s4 = *reinterpret_cast<const float4*>(sinT + tbl + j4*4);
            cs[j4*4+0]=c4.x; cs[j4*4+1]=c4.y; cs[j4*4+2]=c4.z; cs[j4*4+3]=c4.w;
            sn[j4*4+0]=s4.x; sn[j4*4+1]=s4.y; sn[j4*4+2]=s4.z; sn[j4*4+3]=s4.w;
        }
        const u16* srcp = QGKV + tb + 512 + n*HDIM;
        uint4 rr[4];
        #pragma unroll
        for (int ii = 0; ii < 4; ++ii) rr[ii] = reinterpret_cast<const uint4*>(srcp)[ii];
        float v[32]; float ss = 0.f;
        const u32* rw = reinterpret_cast<const u32*>(rr);
        #pragma unroll
        for (int ii = 0; ii < 16; ++ii) {
            v[2*ii]   = bf_lo(rw[ii]);
            v[2*ii+1] = bf_hi(rw[ii]);
            ss += v[2*ii]*v[2*ii] + v[2*ii+1]*v[2*ii+1];
        }
        float rs = rsqrtf(ss*(1.0f/32.0f) + 1e-6f);
        #pragma unroll
        for (int d = 0; d < 32; ++d) v[d] *= rs * knw[d];
        #pragma unroll
        for (int j = 0; j < 16; ++j) {
            float e = v[2*j], o = v[2*j+1];
            v[2*j]   = e*cs[j] - o*sn[j];
            v[2*j+1] = e*sn[j] + o*cs[j];
        }
        int rb = i >> 4, r = i & 15;
        #pragma unroll
        for (int gg = 0; gg < 4; ++gg) {
            uint4 u;
            u.x = (u32)f2bf(v[8*gg+0]) | ((u32)f2bf(v[8*gg+1]) << 16);
            u.y = (u32)f2bf(v[8*gg+2]) | ((u32)f2bf(v[8*gg+3]) << 16);
            u.z = (u32)f2bf(v[8*gg+4]) | ((u32)f2bf(v[8*gg+5]) << 16);
            u.w = (u32)f2bf(v[8*gg+6]) | ((u32)f2bf(v[8*gg+7]) << 16);
            *reinterpret_cast<uint4*>(KL + rb*512 + gg*128 + r*8) = u;
        }
        // V: row-major into two 16-wide d-planes (contiguous b128 writes)
        const uint4* vsrc = reinterpret_cast<const uint4*>(QGKV + tb + 768 + n*HDIM);
        uint4 v0 = vsrc[0], v1 = vsrc[1], v2 = vsrc[2], v3 = vsrc[3];
        *reinterpret_cast<uint4*>(VL + i*16)          = v0;   // d 0..7
        *reinterpret_cast<uint4*>(VL + i*16 + 8)      = v1;   // d 8..15
        *reinterpret_cast<uint4*>(VL + 8192 + i*16)   = v2;   // d 16..23
        *reinterpret_cast<uint4*>(VL + 8192 + i*16+8) = v3;   // d 24..31
    }

    // ---- Q -> registers: lane-parallel norm (shfl butterfly) + rope ----
    short8 qf[4];
    {
        float qw[8];
        {
            float4 a = *reinterpret_cast<const float4*>(qnw + g*8);
            float4 c = *reinterpret_cast<const float4*>(qnw + g*8 + 4);
            qw[0]=a.x; qw[1]=a.y; qw[2]=a.z; qw[3]=a.w;
            qw[4]=c.x; qw[5]=c.y; qw[6]=c.z; qw[7]=c.w;
        }
        #pragma unroll
        for (int qt = 0; qt < 4; ++qt) {
            int hrow = wv*64 + qt*16 + lq;
            union { uint4 u; u32 w[4]; } qr;
            qr.u = *reinterpret_cast<const uint4*>(
                QGKV + ((size_t)(bw*DH + hrow))*1024 + n*HDIM + g*8);
            float v[8]; float ss = 0.f;
            #pragma unroll
            for (int ii = 0; ii < 4; ++ii) {
                v[2*ii]   = bf_lo(qr.w[ii]);
                v[2*ii+1] = bf_hi(qr.w[ii]);
                ss += v[2*ii]*v[2*ii] + v[2*ii+1]*v[2*ii+1];
            }
            ss += __shfl_xor(ss, 16);
            ss += __shfl_xor(ss, 32);
            float rs = rsqrtf(ss*(1.0f/32.0f) + 1e-6f) * CSC;
            int tbl = ((b*DH + hrow)*NHEADS + n)*HALFD + g*4;
            float4 c4 = *reinterpret_cast<const float4*>(cosT + tbl);
            float4 s4 = *reinterpret_cast<const float4*>(sinT + tbl);
            float cs[4] = {c4.x, c4.y, c4.z, c4.w};
            float sn[4] = {s4.x, s4.y, s4.z, s4.w};
            union { short8 s8; u32 w[4]; } o;
            #pragma unroll
            for (int p = 0; p < 4; ++p) {
                float e  = v[2*p]   * rs * qw[2*p];
                float od = v[2*p+1] * rs * qw[2*p+1];
                o.w[p] = cvtpk(e*cs[p] - od*sn[p], e*sn[p] + od*cs[p]);
            }
            qf[qt] = o.s8;
        }
    }
    __syncthreads();

    f32x4 oacc[4][2];
    float l_run[4];
    #pragma unroll
    for (int qt = 0; qt < 4; ++qt) {
        oacc[qt][0] = (f32x4){0.f,0.f,0.f,0.f};
        oacc[qt][1] = (f32x4){0.f,0.f,0.f,0.f};
        l_run[qt] = 0.f;
    }

    u16* PW = PL + wv*1024;                      // 2 x 512 u16 (qt-parity dbuf)
    const int sw = (lq ^ (lq >> 2)) & 3;
    const u32 vbase = (u32)(uintptr_t)VL + (u32)(lq*8 + g*256);

    for (int st = 0; st < 16; ++st) {
        short8 kf[2];
        #pragma unroll
        for (int kt = 0; kt < 2; ++kt) {
            union { uint4 u; short8 s; } c;
            c.u = *reinterpret_cast<const uint4*>(KL + (st*2 + kt)*512 + lane*8);
            kf[kt] = c.s;
        }
        // issue V transpose-reads early
        uint2 v00, v01, v10, v11;
        {
            u32 ta = vbase + (u32)(st*1024);
            asm volatile("ds_read_b64_tr_b16 %0, %4\n\t"
                         "ds_read_b64_tr_b16 %1, %4 offset:128\n\t"
                         "ds_read_b64_tr_b16 %2, %4 offset:16384\n\t"
                         "ds_read_b64_tr_b16 %3, %4 offset:16512"
                         : "=v"(v00), "=v"(v01), "=v"(v10), "=v"(v11)
                         : "v"(ta));
        }
        union { uint4 u; short8 s; } va0, va1;
        #pragma unroll
        for (int qt = 0; qt < 4; ++qt) {
            __builtin_amdgcn_s_setprio(1);
            f32x4 sf0 = __builtin_amdgcn_mfma_f32_16x16x32_bf16(kf[0], qf[qt], (f32x4){0.f,0.f,0.f,0.f}, 0, 0, 0);
            f32x4 sf1 = __builtin_amdgcn_mfma_f32_16x16x32_bf16(kf[1], qf[qt], (f32x4){0.f,0.f,0.f,0.f}, 0, 0, 0);
            __builtin_amdgcn_s_setprio(0);
            float p0 = __builtin_amdgcn_exp2f(sf0[0]);
            float p1 = __builtin_amdgcn_exp2f(sf0[1]);
            float p2 = __builtin_amdgcn_exp2f(sf0[2]);
            float p3 = __builtin_amdgcn_exp2f(sf0[3]);
            float p4 = __builtin_amdgcn_exp2f(sf1[0]);
            float p5 = __builtin_amdgcn_exp2f(sf1[1]);
            float p6 = __builtin_amdgcn_exp2f(sf1[2]);
            float p7 = __builtin_amdgcn_exp2f(sf1[3]);
            l_run[qt] += ((p0+p1)+(p2+p3)) + ((p4+p5)+(p6+p7));
            u16* pq = PW + (qt & 1)*512 + lq*32;
            int ch0 = ((g >> 1)    ) ^ sw;
            int ch1 = ((g >> 1) + 2) ^ sw;
            uint2 w0, w1;
            w0.x = cvtpk(p0, p1); w0.y = cvtpk(p2, p3);
            w1.x = cvtpk(p4, p5); w1.y = cvtpk(p6, p7);
            *reinterpret_cast<uint2*>(pq + ch0*8 + (g&1)*4) = w0;
            *reinterpret_cast<uint2*>(pq + ch1*8 + (g&1)*4) = w1;
            union { uint4 u; short8 s; } pb;
            pb.u = *reinterpret_cast<const uint4*>(pq + (g ^ sw)*8);
            if (qt == 0) {
                asm volatile("s_waitcnt lgkmcnt(0)" ::: "memory");
                __builtin_amdgcn_sched_barrier(0);
                va0.u = make_uint4(v00.x, v00.y, v01.x, v01.y);
                va1.u = make_uint4(v10.x, v10.y, v11.x, v11.y);
            }
            __builtin_amdgcn_s_setprio(1);
            oacc[qt][0] = __builtin_amdgcn_mfma_f32_16x16x32_bf16(va0.s, pb.s, oacc[qt][0], 0, 0, 0);
            oacc[qt][1] = __builtin_amdgcn_mfma_f32_16x16x32_bf16(va1.s, pb.s, oacc[qt][1], 0, 0, 0);
            __builtin_amdgcn_s_setprio(0);
        }
    }

    // ---- epilogue: normalize, gate, store (overwrites q columns) ----
    #pragma unroll
    for (int qt = 0; qt < 4; ++qt) {
        float lr = l_run[qt];
        lr += __shfl_xor(lr, 16);
        lr += __shfl_xor(lr, 32);
        float inv = 1.0f / lr;
        int t = bw*DH + wv*64 + qt*16 + lq;
        size_t tb = (size_t)t*1024;
        #pragma unroll
        for (int df = 0; df < 2; ++df) {
            int col = n*HDIM + 16*df + 4*g;
            ushort4 gv = *reinterpret_cast<const ushort4*>(QGKV + tb + 256 + col);
            u16 gr[4] = {gv.x, gv.y, gv.z, gv.w};
            ushort4 ov;
            u16 orr[4];
            #pragma unroll
            for (int r = 0; r < 4; ++r) {
                float o  = oacc[qt][df][r] * inv;
                float gf = bfu(gr[r]);
                float sg = 1.0f / (1.0f + __builtin_amdgcn_exp2f(-gf * 1.4426950408889634f));
                orr[r] = f2bf_fast(o * sg);
            }
            ov.x = orr[0]; ov.y = orr[1]; ov.z = orr[2]; ov.w = orr[3];
            *reinterpret_cast<ushort4*>(QGKV + tb + col) = ov;
        }
    }
}

// ---------------------------------------------------------------------------
// Kernel 3: MFMA output projection. AG(65536x256 bf16 @ QGKV ld 1024) @ Wo
// + bo -> fp32 out (scattered). Same DMA double-buffer structure, 2 tiles.
// ---------------------------------------------------------------------------
__global__ void __launch_bounds__(256, 1) outproj_mfma_kernel(
    const u16* __restrict__ QGKV, const u16* __restrict__ Wofl,
    const float* __restrict__ bo, float* __restrict__ out)
{
    __shared__ u16 BUF[2][32768];   // 128 KiB
    int tid = threadIdx.x;
    int rt  = blockIdx.x;
    int lane = tid & 63, wv = tid >> 6;
    int g = lane >> 4, lq = lane & 15;
    int rhalf = wv >> 1, cstrip = wv & 1;

    // issue Wot tile0 -> BUF[0]
    #pragma unroll
    for (int r = 0; r < 16; ++r)
        gload_lds16(Wofl + (r*256 + tid)*8, &BUF[0][(r*256 + tid)*8]);
    __builtin_amdgcn_sched_barrier(0);

    // stage A -> BUF[1] (bf16 frag-linear)
    {
        int i  = tid >> 1;
        int kg = tid & 1;
        const u16* arow = QGKV + (size_t)(rt*128 + i)*1024;
        int rb = i >> 4, r = i & 15;
        #pragma unroll
        for (int kk = 0; kk < 16; ++kk) {
            int k0 = kg*128 + kk*8;
            uint4 u = *reinterpret_cast<const uint4*>(arow + k0);
            int ks = k0 >> 5, gg = (k0 >> 3) & 3;
            *reinterpret_cast<uint4*>(&BUF[1][(ks*8+rb)*512 + (gg*16+r)*8]) = u;
        }
    }
    __syncthreads();

    short8 xf[4][8];
    #pragma unroll
    for (int tf = 0; tf < 4; ++tf)
        #pragma unroll
        for (int ks = 0; ks < 8; ++ks) {
            union { uint4 u; short8 s; } c;
            c.u = *reinterpret_cast<const uint4*>(&BUF[1][(ks*8 + rhalf*4 + tf)*512 + lane*8]);
            xf[tf][ks] = c.s;
        }
    asm volatile("s_waitcnt lgkmcnt(0)" ::: "memory");
    __builtin_amdgcn_sched_barrier(0);
    asm volatile("s_waitcnt vmcnt(0)" ::: "memory");
    __syncthreads();

    for (int ct = 0; ct < 2; ++ct) {
        u16* cur = BUF[ct & 1];
        u16* nxt = BUF[(ct & 1) ^ 1];
        if (ct + 1 < 2) {
            const u16* src = Wofl + (size_t)(ct + 1)*32768;
            #pragma unroll
            for (int r = 0; r < 16; ++r)
                gload_lds16(src + (r*256 + tid)*8, &nxt[(r*256 + tid)*8]);
        }
        __builtin_amdgcn_sched_barrier(0);

        int nbase = ct*128 + cstrip*64;
        f32x4 acc[4][4];
        #pragma unroll
        for (int a = 0; a < 4; ++a)
            #pragma unroll
            for (int bb = 0; bb < 4; ++bb) acc[a][bb] = (f32x4){0.f,0.f,0.f,0.f};

        #pragma unroll
        for (int ks = 0; ks < 8; ++ks) {
            short8 wf[4];
            #pragma unroll
            for (int nf = 0; nf < 4; ++nf) {
                union { uint4 u; short8 s; } c;
                c.u = *reinterpret_cast<const uint4*>(&cur[(ks*8 + cstrip*4 + nf)*512 + lane*8]);
                wf[nf] = c.s;
            }
            #pragma unroll
            for (int tf = 0; tf < 4; ++tf)
                #pragma unroll
                for (int nf = 0; nf < 4; ++nf)
                    acc[tf][nf] = __builtin_amdgcn_mfma_f32_16x16x32_bf16(wf[nf], xf[tf][ks], acc[tf][nf], 0, 0, 0);
        }
        #pragma unroll
        for (int tf = 0; tf < 4; ++tf) {
            int trow = rt*128 + (rhalf*4 + tf)*16 + lq;
            int bw = trow >> 9, h = trow & 511, b = bw >> 6, w = bw & 63;
            float* orow = out + ((size_t)((b*DH + h)*DW + w))*DC;
            #pragma unroll
            for (int nf = 0; nf < 4; ++nf) {
                int nn = nbase + nf*16 + g*4;
                float4 bv = *reinterpret_cast<const float4*>(bo + nn);
                float4 res;
                res.x = acc[tf][nf][0] + bv.x;
                res.y = acc[tf][nf][1] + bv.y;
                res.z = acc[tf][nf][2] + bv.z;
                res.w = acc[tf][nf][3] + bv.w;
                *reinterpret_cast<float4*>(orow + nn) = res;
            }
        }
        asm volatile("s_waitcnt vmcnt(0)" ::: "memory");
        __syncthreads();
    }
}

// ---------------------------------------------------------------------------
extern "C" void kernel_launch(void* const* d_in, const int* in_sizes, int n_in,
                              void* d_out, int out_size, void* d_ws, size_t ws_size,
                              hipStream_t stream)
{
    const float* x      = (const float*)d_in[0];
    const float* pos    = (const float*)d_in[1];
    const float* Wq     = (const float*)d_in[2];
    const float* Wk     = (const float*)d_in[3];
    const float* Wv     = (const float*)d_in[4];
    const float* Wo     = (const float*)d_in[5];
    const float* bo     = (const float*)d_in[6];
    const float* qnw    = (const float*)d_in[7];
    const float* knw    = (const float*)d_in[8];
    const float* rope_w = (const float*)d_in[9];
    const float* rope_b = (const float*)d_in[10];
    float* out = (float*)d_out;

    char* wsp = (char*)d_ws;
    u16*   QGKV = (u16*)wsp;                                  // 128 MiB
    float* cosT = (float*)(wsp + (size_t)NTOK*1024*2);        // 512 KiB
    float* sinT = cosT + DB*DH*NHEADS*HALFD;                  // 512 KiB
    u16*   Wfl  = (u16*)(sinT + DB*DH*NHEADS*HALFD);          // 512 KiB (8 tiles)
    u16*   Wofl = Wfl + 8*32768;                              // 128 KiB (2 tiles)

    prep_kernel        <<<dim3(672),  dim3(256), 0, stream>>>(pos, rope_w, rope_b, cosT, sinT,
                                                              Wq, Wk, Wv, Wo, Wfl, Wofl);
    proj_mfma_kernel   <<<dim3(512),  dim3(256), 0, stream>>>(x, Wfl, QGKV);
    attn_kernel        <<<dim3(1024), dim3(512), 0, stream>>>(QGKV, qnw, knw, cosT, sinT);
    outproj_mfma_kernel<<<dim3(512),  dim3(256), 0, stream>>>(QGKV, Wofl, bo, out);
}